// Round 1
// baseline (39.740 us; speedup 1.0000x reference)
//
#include <hip/hip_runtime.h>

#define B 8
#define S 2048
#define NBLK_PER_SAMPLE 128
#define TPB2 256

__device__ __forceinline__ float sigmoid_fast(float z) {
    // matches jax.nn.sigmoid within f32 noise; saturates correctly:
    // __expf(+huge)=inf -> 1/(1+inf)=0 ; __expf(-huge)=0 -> 1
    return 1.0f / (1.0f + __expf(-z));
}

// ---------------------------------------------------------------------------
// Kernel 1: per-element losses + stable compaction of point_pred by non_none.
// One block per sample (8 blocks x 1024 threads, 2 elements/thread).
// ---------------------------------------------------------------------------
__global__ __launch_bounds__(1024) void per_elem_kernel(
    const float2* __restrict__ point_pred,
    const float2* __restrict__ orient_pred,
    const float4* __restrict__ class_pred,
    const float*  __restrict__ target_seq,
    const int*    __restrict__ padding_mask,
    float* __restrict__ acc,     // [0]=cls [1]=pt [2]=orient [3]=inter [4]=valid_cnt [5]=nn_cnt
    int*   __restrict__ n_buf,   // [B]
    float2* __restrict__ pts_c)  // [B][S]
{
    const int b = blockIdx.x;
    const int tid = threadIdx.x;
    const int base = b * S;

    float cls_acc = 0.f, pt_acc = 0.f, or_acc = 0.f, v_acc = 0.f, nn_acc = 0.f;
    int f0 = 0, f1 = 0;
    float2 p0 = make_float2(0.f, 0.f), p1 = make_float2(0.f, 0.f);

    #pragma unroll
    for (int k = 0; k < 2; ++k) {
        const int e = tid * 2 + k;
        const int idx = base + e;
        const bool valid = (padding_mask[idx] == 0);
        const float t4 = target_seq[idx * 5 + 4];
        const int tc = (int)t4;
        const bool nn = valid && (tc != 0);
        const float2 pp = point_pred[idx];
        if (k == 0) { f0 = nn ? 1 : 0; p0 = pp; } else { f1 = nn ? 1 : 0; p1 = pp; }
        if (valid) {
            const float4 c = class_pred[idx];
            const float m = fmaxf(fmaxf(c.x, c.y), fmaxf(c.z, c.w));
            const float lse = m + logf(expf(c.x - m) + expf(c.y - m) +
                                       expf(c.z - m) + expf(c.w - m));
            const float ct = (tc == 0) ? c.x : (tc == 1) ? c.y : (tc == 2) ? c.z : c.w;
            cls_acc += lse - ct;
            v_acc += 1.f;
        }
        if (nn) {
            const float tx = target_seq[idx * 5 + 0];
            const float ty = target_seq[idx * 5 + 1];
            const float dx = (pp.x - tx) * (1.0f / 224.0f);
            const float dy = (pp.y - ty) * (1.0f / 224.0f);
            const float adx = fabsf(dx), ady = fabsf(dy);
            const float l0 = (adx < 1.f) ? 0.5f * dx * dx : adx - 0.5f;
            const float l1 = (ady < 1.f) ? 0.5f * dy * dy : ady - 0.5f;
            pt_acc += 0.5f * (l0 + l1);
            const float2 op = orient_pred[idx];
            const float ox = target_seq[idx * 5 + 2];
            const float oy = target_seq[idx * 5 + 3];
            or_acc += 1.f - (op.x * ox + op.y * oy);
            nn_acc += 1.f;
        }
    }

    // ---- block-wide exclusive scan over flags (stable compaction) ----
    const int lane = tid & 63;
    const int wv = tid >> 6;
    const int tsum = f0 + f1;
    int inc = tsum;
    #pragma unroll
    for (int off = 1; off < 64; off <<= 1) {
        int u = __shfl_up(inc, (unsigned)off, 64);
        if (lane >= off) inc += u;
    }
    __shared__ int wsum[16], woff[16];
    if (lane == 63) wsum[wv] = inc;
    __syncthreads();
    if (tid == 0) {
        int run = 0;
        #pragma unroll
        for (int w = 0; w < 16; ++w) { woff[w] = run; run += wsum[w]; }
        n_buf[b] = run;
    }
    __syncthreads();
    const int pos = woff[wv] + (inc - tsum);
    if (f0) pts_c[base + pos] = p0;
    if (f1) pts_c[base + pos + f0] = p1;

    // ---- block reduce the 5 partials ----
    #pragma unroll
    for (int off = 32; off > 0; off >>= 1) {
        cls_acc += __shfl_down(cls_acc, (unsigned)off, 64);
        pt_acc  += __shfl_down(pt_acc,  (unsigned)off, 64);
        or_acc  += __shfl_down(or_acc,  (unsigned)off, 64);
        v_acc   += __shfl_down(v_acc,   (unsigned)off, 64);
        nn_acc  += __shfl_down(nn_acc,  (unsigned)off, 64);
    }
    __shared__ float red[16][5];
    if (lane == 0) {
        red[wv][0] = cls_acc; red[wv][1] = pt_acc; red[wv][2] = or_acc;
        red[wv][3] = v_acc;   red[wv][4] = nn_acc;
    }
    __syncthreads();
    if (tid == 0) {
        float s0 = 0, s1 = 0, s2 = 0, s3 = 0, s4 = 0;
        #pragma unroll
        for (int w = 0; w < 16; ++w) {
            s0 += red[w][0]; s1 += red[w][1]; s2 += red[w][2];
            s3 += red[w][3]; s4 += red[w][4];
        }
        atomicAdd(&acc[0], s0);
        atomicAdd(&acc[1], s1);
        atomicAdd(&acc[2], s2);
        atomicAdd(&acc[4], s3);
        atomicAdd(&acc[5], s4);
    }
}

// ---------------------------------------------------------------------------
// Kernel 2: soft segment-intersection sum over the pair triangle.
// NBLK_PER_SAMPLE blocks per sample; i strided by NBLK_PER_SAMPLE for balance.
// Compacted points staged in LDS (<=16 KB).
// ---------------------------------------------------------------------------
__global__ __launch_bounds__(TPB2) void inter_kernel(
    const float2* __restrict__ pts_c,
    const int* __restrict__ n_buf,
    float* __restrict__ acc)
{
    const int b = blockIdx.x / NBLK_PER_SAMPLE;
    const int iblk = blockIdx.x % NBLK_PER_SAMPLE;
    const int n = n_buf[b];
    if (n < 4) return;               // uniform across block
    const int n_seg = n - 1;
    const int tid = threadIdx.x;

    __shared__ float2 sp[S];
    for (int k = tid; k < n; k += TPB2) sp[k] = pts_c[b * S + k];
    __syncthreads();

    float local = 0.f;
    for (int i = iblk; i < n_seg - 2; i += NBLK_PER_SAMPLE) {
        const float2 q1 = sp[i];
        const float2 q2 = sp[i + 1];
        const float e12x = q2.x - q1.x, e12y = q2.y - q1.y;
        for (int j = i + 2 + tid; j < n_seg; j += TPB2) {
            if (i == 0 && j == n_seg - 1) continue;   // excluded wrap pair
            const float2 q3 = sp[j];
            const float2 q4 = sp[j + 1];
            const float e34x = q4.x - q3.x, e34y = q4.y - q3.y;
            const float d1 = e34x * (q1.y - q3.y) - e34y * (q1.x - q3.x);
            const float d2 = e34x * (q2.y - q3.y) - e34y * (q2.x - q3.x);
            const float d3 = e12x * (q3.y - q1.y) - e12y * (q3.x - q1.x);
            const float d4 = e12x * (q4.y - q1.y) - e12y * (q4.x - q1.x);
            local += sigmoid_fast(-d1 * d2 * 0.01f) * sigmoid_fast(-d3 * d4 * 0.01f);
        }
    }

    const int lane = tid & 63, wv = tid >> 6;
    #pragma unroll
    for (int off = 32; off > 0; off >>= 1)
        local += __shfl_down(local, (unsigned)off, 64);
    __shared__ float r[TPB2 / 64];
    if (lane == 0) r[wv] = local;
    __syncthreads();
    if (tid == 0) {
        float s = 0.f;
        #pragma unroll
        for (int w = 0; w < TPB2 / 64; ++w) s += r[w];
        atomicAdd(&acc[3], s);
    }
}

// ---------------------------------------------------------------------------
// Kernel 3: finalize the 5 scalar outputs. Count is closed-form.
// ---------------------------------------------------------------------------
__global__ void finalize_kernel(const float* __restrict__ acc,
                                const int* __restrict__ n_buf,
                                float* __restrict__ out)
{
    if (threadIdx.x == 0 && blockIdx.x == 0) {
        const float cls_sum = acc[0], pt_sum = acc[1], or_sum = acc[2], inter_sum = acc[3];
        const float vcnt = acc[4], nncnt = acc[5];
        long long cnt = 0;
        for (int b = 0; b < B; ++b) {
            const int n = n_buf[b];
            if (n >= 4) {
                const long long ns = n - 1;
                cnt += (ns - 1) * (ns - 2) / 2 - 1;
            }
        }
        const float cls_loss = cls_sum / fmaxf(vcnt, 1.f);
        const float pt_loss = pt_sum / fmaxf(nncnt, 1.f);
        const float orient_loss = or_sum / fmaxf(nncnt, 1.f);
        const float intersect_loss = (cnt > 0) ? inter_sum / (float)cnt : 0.f;
        const float total = 1.0f * pt_loss + 0.5f * orient_loss +
                            1.0f * cls_loss + 0.1f * intersect_loss;
        out[0] = total;
        out[1] = pt_loss;
        out[2] = orient_loss;
        out[3] = cls_loss;
        out[4] = intersect_loss;
    }
}

extern "C" void kernel_launch(void* const* d_in, const int* in_sizes, int n_in,
                              void* d_out, int out_size, void* d_ws, size_t ws_size,
                              hipStream_t stream) {
    (void)in_sizes; (void)n_in; (void)out_size; (void)ws_size;
    const float2* point_pred  = (const float2*)d_in[0];
    const float2* orient_pred = (const float2*)d_in[1];
    const float4* class_pred  = (const float4*)d_in[2];
    const float*  target_seq  = (const float*)d_in[3];
    const int*    padding_mask = (const int*)d_in[4];

    float*  acc   = (float*)d_ws;                    // 6 floats
    int*    n_buf = (int*)((char*)d_ws + 64);        // B ints
    float2* pts_c = (float2*)((char*)d_ws + 256);    // B*S float2

    hipMemsetAsync(d_ws, 0, 64, stream);

    per_elem_kernel<<<B, 1024, 0, stream>>>(point_pred, orient_pred, class_pred,
                                            target_seq, padding_mask,
                                            acc, n_buf, pts_c);
    inter_kernel<<<B * NBLK_PER_SAMPLE, TPB2, 0, stream>>>(pts_c, n_buf, acc);
    finalize_kernel<<<1, 64, 0, stream>>>(acc, n_buf, (float*)d_out);
}

// Round 2
// 25.254 us; speedup vs baseline: 1.5736x; 1.5736x over previous
//
#include <hip/hip_runtime.h>

#define B 8
#define S 2048
#define NBLK_PER_SAMPLE 128
#define TPB2 256
#define NBLK2 (B * NBLK_PER_SAMPLE)

// ---------------------------------------------------------------------------
// Workspace layout (all slots written every launch -> no zeroing needed):
//   [0,160)      float acc1[8][5]   per-sample {cls, pt, orient, valid, nn}
//   [192,224)    int   n_buf[8]
//   [256,4352)   float partial[1024] per-block intersection partials
//   [4608, +128K) float2 pts_c[8][2048] compacted points
// ---------------------------------------------------------------------------

// ---------------------------------------------------------------------------
// Kernel 1: per-element losses + stable compaction of point_pred by non_none.
// One block per sample (8 blocks x 1024 threads, 2 elements/thread).
// ---------------------------------------------------------------------------
__global__ __launch_bounds__(1024) void per_elem_kernel(
    const float2* __restrict__ point_pred,
    const float2* __restrict__ orient_pred,
    const float4* __restrict__ class_pred,
    const float*  __restrict__ target_seq,
    const int*    __restrict__ padding_mask,
    float* __restrict__ acc1,    // [B][5]
    int*   __restrict__ n_buf,   // [B]
    float2* __restrict__ pts_c)  // [B][S]
{
    const int b = blockIdx.x;
    const int tid = threadIdx.x;
    const int base = b * S;

    float cls_acc = 0.f, pt_acc = 0.f, or_acc = 0.f, v_acc = 0.f, nn_acc = 0.f;
    int f0 = 0, f1 = 0;
    float2 p0 = make_float2(0.f, 0.f), p1 = make_float2(0.f, 0.f);

    #pragma unroll
    for (int k = 0; k < 2; ++k) {
        const int e = tid * 2 + k;
        const int idx = base + e;
        const bool valid = (padding_mask[idx] == 0);
        const float t4 = target_seq[idx * 5 + 4];
        const int tc = (int)t4;
        const bool nn = valid && (tc != 0);
        const float2 pp = point_pred[idx];
        if (k == 0) { f0 = nn ? 1 : 0; p0 = pp; } else { f1 = nn ? 1 : 0; p1 = pp; }
        if (valid) {
            const float4 c = class_pred[idx];
            const float m = fmaxf(fmaxf(c.x, c.y), fmaxf(c.z, c.w));
            const float lse = m + logf(expf(c.x - m) + expf(c.y - m) +
                                       expf(c.z - m) + expf(c.w - m));
            const float ct = (tc == 0) ? c.x : (tc == 1) ? c.y : (tc == 2) ? c.z : c.w;
            cls_acc += lse - ct;
            v_acc += 1.f;
        }
        if (nn) {
            const float tx = target_seq[idx * 5 + 0];
            const float ty = target_seq[idx * 5 + 1];
            const float dx = (pp.x - tx) * (1.0f / 224.0f);
            const float dy = (pp.y - ty) * (1.0f / 224.0f);
            const float adx = fabsf(dx), ady = fabsf(dy);
            const float l0 = (adx < 1.f) ? 0.5f * dx * dx : adx - 0.5f;
            const float l1 = (ady < 1.f) ? 0.5f * dy * dy : ady - 0.5f;
            pt_acc += 0.5f * (l0 + l1);
            const float2 op = orient_pred[idx];
            const float ox = target_seq[idx * 5 + 2];
            const float oy = target_seq[idx * 5 + 3];
            or_acc += 1.f - (op.x * ox + op.y * oy);
            nn_acc += 1.f;
        }
    }

    // ---- block-wide exclusive scan over flags (stable compaction) ----
    const int lane = tid & 63;
    const int wv = tid >> 6;
    const int tsum = f0 + f1;
    int inc = tsum;
    #pragma unroll
    for (int off = 1; off < 64; off <<= 1) {
        int u = __shfl_up(inc, (unsigned)off, 64);
        if (lane >= off) inc += u;
    }
    __shared__ int wsum[16], woff[16];
    if (lane == 63) wsum[wv] = inc;
    __syncthreads();
    if (tid == 0) {
        int run = 0;
        #pragma unroll
        for (int w = 0; w < 16; ++w) { woff[w] = run; run += wsum[w]; }
        n_buf[b] = run;
    }
    __syncthreads();
    const int pos = woff[wv] + (inc - tsum);
    if (f0) pts_c[base + pos] = p0;
    if (f1) pts_c[base + pos + f0] = p1;

    // ---- block reduce the 5 partials -> slot write (no atomics) ----
    #pragma unroll
    for (int off = 32; off > 0; off >>= 1) {
        cls_acc += __shfl_down(cls_acc, (unsigned)off, 64);
        pt_acc  += __shfl_down(pt_acc,  (unsigned)off, 64);
        or_acc  += __shfl_down(or_acc,  (unsigned)off, 64);
        v_acc   += __shfl_down(v_acc,   (unsigned)off, 64);
        nn_acc  += __shfl_down(nn_acc,  (unsigned)off, 64);
    }
    __shared__ float red[16][5];
    if (lane == 0) {
        red[wv][0] = cls_acc; red[wv][1] = pt_acc; red[wv][2] = or_acc;
        red[wv][3] = v_acc;   red[wv][4] = nn_acc;
    }
    __syncthreads();
    if (tid == 0) {
        float s0 = 0, s1 = 0, s2 = 0, s3 = 0, s4 = 0;
        #pragma unroll
        for (int w = 0; w < 16; ++w) {
            s0 += red[w][0]; s1 += red[w][1]; s2 += red[w][2];
            s3 += red[w][3]; s4 += red[w][4];
        }
        acc1[b * 5 + 0] = s0;
        acc1[b * 5 + 1] = s1;
        acc1[b * 5 + 2] = s2;
        acc1[b * 5 + 3] = s3;
        acc1[b * 5 + 4] = s4;
    }
}

// ---------------------------------------------------------------------------
// Kernel 2: soft segment-intersection sum. Segments staged in LDS as
// float4{start.x, start.y, edge.x, edge.y} -> one ds_read_b128 per pair.
// d2/d4 derived from d1/d3 via the edge-cross identity.
// ---------------------------------------------------------------------------
__global__ __launch_bounds__(TPB2) void inter_kernel(
    const float2* __restrict__ pts_c,
    const int* __restrict__ n_buf,
    float* __restrict__ partial)
{
    __shared__ float4 seg[S - 1];      // 32752 B
    const int b = blockIdx.x / NBLK_PER_SAMPLE;
    const int iblk = blockIdx.x % NBLK_PER_SAMPLE;
    const int n = n_buf[b];
    const int tid = threadIdx.x;
    float local = 0.f;

    if (n >= 4) {                       // uniform across block
        const int n_seg = n - 1;
        const float2* pb = pts_c + b * S;
        for (int k = tid; k < n_seg; k += TPB2) {
            const float2 p = pb[k];
            const float2 q = pb[k + 1];
            seg[k] = make_float4(p.x, p.y, q.x - p.x, q.y - p.y);
        }
        __syncthreads();

        for (int i = iblk; i < n_seg - 2; i += NBLK_PER_SAMPLE) {
            const float4 s1 = seg[i];   // q1=(x,y), e12=(z,w)
            for (int j = i + 2 + tid; j < n_seg; j += TPB2) {
                if (i == 0 && j == n_seg - 1) continue;   // excluded wrap pair
                const float4 s3 = seg[j];                 // q3=(x,y), e34=(z,w)
                const float ce = s1.z * s3.w - s1.w * s3.z;   // cross(e12,e34)
                const float rx = s1.x - s3.x;                 // q1 - q3
                const float ry = s1.y - s3.y;
                const float d1 = s3.z * ry - s3.w * rx;
                const float d3 = s1.w * rx - s1.z * ry;
                const float d2 = d1 - ce;
                const float d4 = d3 + ce;
                const float ea = __expf(d1 * d2 * 0.01f);     // exp(-z1)
                const float eb = __expf(d3 * d4 * 0.01f);     // exp(-z2)
                // sigmoid(z1)*sigmoid(z2) = 1/((1+ea)(1+eb)); inf -> rcp -> 0 ok
                local += __builtin_amdgcn_rcpf((1.f + ea) * (1.f + eb));
            }
        }
    }

    const int lane = tid & 63, wv = tid >> 6;
    #pragma unroll
    for (int off = 32; off > 0; off >>= 1)
        local += __shfl_down(local, (unsigned)off, 64);
    __shared__ float r[TPB2 / 64];
    if (lane == 0) r[wv] = local;
    __syncthreads();
    if (tid == 0) {
        float s = 0.f;
        #pragma unroll
        for (int w = 0; w < TPB2 / 64; ++w) s += r[w];
        partial[blockIdx.x] = s;        // slot write, no atomic, no pre-zero
    }
}

// ---------------------------------------------------------------------------
// Kernel 3: reduce 1024 intersection partials + 8x5 per-sample partials,
// closed-form pair count, write the 5 outputs.
// ---------------------------------------------------------------------------
__global__ __launch_bounds__(256) void finalize_kernel(
    const float* __restrict__ acc1,
    const int* __restrict__ n_buf,
    const float* __restrict__ partial,
    float* __restrict__ out)
{
    const int tid = threadIdx.x;
    float s = 0.f;
    #pragma unroll
    for (int k = 0; k < NBLK2 / 256; ++k) s += partial[tid + 256 * k];
    const int lane = tid & 63, wv = tid >> 6;
    #pragma unroll
    for (int off = 32; off > 0; off >>= 1)
        s += __shfl_down(s, (unsigned)off, 64);
    __shared__ float r[4];
    if (lane == 0) r[wv] = s;
    __syncthreads();
    if (tid == 0) {
        const float inter_sum = r[0] + r[1] + r[2] + r[3];
        float cls_sum = 0, pt_sum = 0, or_sum = 0, vcnt = 0, nncnt = 0;
        #pragma unroll
        for (int b2 = 0; b2 < B; ++b2) {
            cls_sum += acc1[b2 * 5 + 0];
            pt_sum  += acc1[b2 * 5 + 1];
            or_sum  += acc1[b2 * 5 + 2];
            vcnt    += acc1[b2 * 5 + 3];
            nncnt   += acc1[b2 * 5 + 4];
        }
        long long cnt = 0;
        #pragma unroll
        for (int b2 = 0; b2 < B; ++b2) {
            const int n = n_buf[b2];
            if (n >= 4) {
                const long long ns = n - 1;
                cnt += (ns - 1) * (ns - 2) / 2 - 1;
            }
        }
        const float cls_loss = cls_sum / fmaxf(vcnt, 1.f);
        const float pt_loss = pt_sum / fmaxf(nncnt, 1.f);
        const float orient_loss = or_sum / fmaxf(nncnt, 1.f);
        const float intersect_loss = (cnt > 0) ? inter_sum / (float)cnt : 0.f;
        const float total = 1.0f * pt_loss + 0.5f * orient_loss +
                            1.0f * cls_loss + 0.1f * intersect_loss;
        out[0] = total;
        out[1] = pt_loss;
        out[2] = orient_loss;
        out[3] = cls_loss;
        out[4] = intersect_loss;
    }
}

extern "C" void kernel_launch(void* const* d_in, const int* in_sizes, int n_in,
                              void* d_out, int out_size, void* d_ws, size_t ws_size,
                              hipStream_t stream) {
    (void)in_sizes; (void)n_in; (void)out_size; (void)ws_size;
    const float2* point_pred  = (const float2*)d_in[0];
    const float2* orient_pred = (const float2*)d_in[1];
    const float4* class_pred  = (const float4*)d_in[2];
    const float*  target_seq  = (const float*)d_in[3];
    const int*    padding_mask = (const int*)d_in[4];

    float*  acc1    = (float*)d_ws;                     // 8*5 floats
    int*    n_buf   = (int*)((char*)d_ws + 192);        // B ints
    float*  partial = (float*)((char*)d_ws + 256);      // 1024 floats
    float2* pts_c   = (float2*)((char*)d_ws + 4608);    // B*S float2

    per_elem_kernel<<<B, 1024, 0, stream>>>(point_pred, orient_pred, class_pred,
                                            target_seq, padding_mask,
                                            acc1, n_buf, pts_c);
    inter_kernel<<<NBLK2, TPB2, 0, stream>>>(pts_c, n_buf, partial);
    finalize_kernel<<<1, 256, 0, stream>>>(acc1, n_buf, partial, (float*)d_out);
}